// Round 4
// baseline (1472.089 us; speedup 1.0000x reference)
//
#include <hip/hip_runtime.h>
#include <hip/hip_fp8.h>
#include <stdint.h>

typedef __bf16 bf16_t;
typedef bf16_t bf16x8 __attribute__((ext_vector_type(8)));
typedef bf16_t bf16x4 __attribute__((ext_vector_type(4)));
typedef float  f32x4  __attribute__((ext_vector_type(4)));

#define MFMA_BF16(a,b,c) __builtin_amdgcn_mfma_f32_16x16x32_bf16(a,b,c,0,0,0)

// async global->LDS, 16B/lane; LDS base wave-uniform (HW adds lane*16)
__device__ __forceinline__ void load_lds16(const bf16_t* g, bf16_t* l) {
  __builtin_amdgcn_global_load_lds((const __attribute__((address_space(1))) void*)g,
                                   (__attribute__((address_space(3))) void*)l,
                                   16, 0, 0);
}

__device__ __forceinline__ float fp8_to_f(uint8_t b) {
  return (float)__builtin_bit_cast(__hip_fp8_e4m3, b);
}
__device__ __forceinline__ uint8_t f_to_fp8(float f) {
  return __builtin_bit_cast(uint8_t, __hip_fp8_e4m3(f));
}
// SCALED residual codec: bf16 residual of O(1) data is ~2^-9 -- inside e4m3's
// denormal floor. Scale by 256 so the residual sits in e4m3 normal range
// (rel err 2^-4 on r -> effective 1.2e-4 on the value). Decode is exact.
__device__ __forceinline__ uint8_t fp8s_enc(float r) { return f_to_fp8(r * 256.f); }
__device__ __forceinline__ float   fp8s_dec(uint8_t b) { return fp8_to_f(b) * (1.f/256.f); }

// ---------------------------------------------------------------------------
// W f32 -> Whi bf16 + Wlo bf16 (full bf16 residual). Layout [p][depth][o][c].
// ---------------------------------------------------------------------------
__global__ __launch_bounds__(256) void cast_w_kern(const float* __restrict__ wq,
    const float* __restrict__ wk, const float* __restrict__ wv,
    bf16_t* __restrict__ whi, bf16_t* __restrict__ wlo) {
  const int i = blockIdx.x * 256 + threadIdx.x;
  const int idx = i * 4;
  const int p = idx / 786432;
  const int r = idx - p * 786432;
  const float* s = (p == 0 ? wq : (p == 1 ? wk : wv));
  float4 v = *(const float4*)(s + r);
  float f[4] = {v.x, v.y, v.z, v.w};
  bf16x4 hi, lo;
#pragma unroll
  for (int j = 0; j < 4; ++j) {
    bf16_t h = (bf16_t)f[j];
    hi[j] = h;
    lo[j] = (bf16_t)(f[j] - (float)h);
  }
  const size_t o = (size_t)p * 786432 + r;
  *(bf16x4*)(whi + o) = hi;
  *(bf16x4*)(wlo + o) = lo;
}

// P[b][c][l] f32 -> x[b][l][c] bf16-hi + scaled-fp8-lo
__global__ __launch_bounds__(256) void transpose_split_in_kern(
    const float* __restrict__ P, bf16_t* __restrict__ xh, uint8_t* __restrict__ xl) {
  __shared__ float t[32][33];
  const int bz = blockIdx.x >> 8;
  const int ti = blockIdx.x & 255;
  const int tc = (ti >> 4) * 32;
  const int tl = (ti & 15) * 32;
  const float* Pb = P + (size_t)bz * 262144;
  bf16_t* xb = xh + (size_t)bz * 262144;
  uint8_t* lb = xl + (size_t)bz * 262144;
  const int tx = threadIdx.x & 31, ty = threadIdx.x >> 5;
#pragma unroll
  for (int k = 0; k < 4; ++k)
    t[ty*4+k][tx] = Pb[(size_t)(tc + ty*4 + k)*512 + tl + tx];
  __syncthreads();
#pragma unroll
  for (int k = 0; k < 4; ++k) {
    const float f = t[tx][ty*4+k];
    const bf16_t h = (bf16_t)f;
    const size_t o = (size_t)(tl + ty*4 + k)*512 + tc + tx;
    xb[o] = h;
    lb[o] = fp8s_enc(f - (float)h);
  }
}

// ---------------------------------------------------------------------------
// Proj GEMM: y[p][b][o][l] = W_p[o][c] . x[b][l][c] + bias (3-term hi/lo)
// p<2: store hi + scaled-fp8 lo (pre-norm Q/K). p==2: Yv hi + BF16 lo.
// ---------------------------------------------------------------------------
__global__ __launch_bounds__(256) void gemm_qkv_kern(
    const bf16_t* __restrict__ Whi, const bf16_t* __restrict__ Wlo,
    const bf16_t* __restrict__ xh, const uint8_t* __restrict__ xl,
    const float* __restrict__ bq, const float* __restrict__ bk,
    const float* __restrict__ bv, int depth,
    bf16_t* __restrict__ Qh, uint8_t* __restrict__ Ql,
    bf16_t* __restrict__ Kh, uint8_t* __restrict__ Kl,
    bf16_t* __restrict__ Yvh, bf16_t* __restrict__ Yvl) {
  __shared__ __align__(16) bf16_t Ah[4096], Al[4096], Bh[4096], Bl[4096];
  const int blk = blockIdx.x;
  const int t  = blk & 15;
  const int pb = blk >> 4;
  const int b  = pb & 63, p = pb >> 6;
  const int row0 = (t >> 2) * 128, col0 = (t & 3) * 128;
  const size_t woff = (size_t)p * 786432 + (size_t)depth * 262144;
  const bf16_t* A_hi = Whi + woff;
  const bf16_t* A_lo = Wlo + woff;
  const bf16_t* B_hi = xh + (size_t)b * 262144;
  const uint8_t* B_lo = xl + (size_t)b * 262144;
  const int tid = threadIdx.x, lane = tid & 63, wid = tid >> 6;
  const int wm = wid >> 1, wn = wid & 1;
  const int sr = tid >> 2, scs = (tid & 3) * 8;
  const int frow = lane & 15, fk = (lane >> 4) * 8;
  const int lrow = tid >> 1, lhalf = (tid & 1) * 16;
  f32x4 acc[4][4] = {};
  bf16_t* lah = Ah + wid * 512;
  bf16_t* lal = Al + wid * 512;
  bf16_t* lbh = Bh + wid * 512;
  const bf16_t* gah = A_hi + (size_t)(row0 + sr) * 512 + scs;
  const bf16_t* gal = A_lo + (size_t)(row0 + sr) * 512 + scs;
  const bf16_t* gbh = B_hi + (size_t)(col0 + sr) * 512 + scs;
  const uint8_t* gbl = B_lo + (size_t)(col0 + lrow) * 512 + lhalf;
  for (int ks = 0; ks < 16; ++ks) {
    const int k0 = ks * 32;
    load_lds16(gah + k0, lah); load_lds16(gah + 32768 + k0, lah + 2048);
    load_lds16(gal + k0, lal); load_lds16(gal + 32768 + k0, lal + 2048);
    load_lds16(gbh + k0, lbh); load_lds16(gbh + 32768 + k0, lbh + 2048);
    { // reg-stage scaled-fp8 x-lo tile -> bf16 LDS
      uint4 raw = *(const uint4*)(gbl + k0);
      uint8_t by[16]; *(uint4*)by = raw;
      bf16x8 v0, v1;
#pragma unroll
      for (int j = 0; j < 8; ++j) v0[j] = (bf16_t)fp8s_dec(by[j]);
#pragma unroll
      for (int j = 0; j < 8; ++j) v1[j] = (bf16_t)fp8s_dec(by[8+j]);
      *(bf16x8*)(Bl + lrow*32 + lhalf)     = v0;
      *(bf16x8*)(Bl + lrow*32 + lhalf + 8) = v1;
    }
    __syncthreads();
    bf16x8 ah[4], al[4], bh[4], bl[4];
#pragma unroll
    for (int i = 0; i < 4; ++i) {
      const int ai = (wm*64 + i*16 + frow)*32 + fk;
      const int bi = (wn*64 + i*16 + frow)*32 + fk;
      ah[i] = *(const bf16x8*)(Ah + ai);
      al[i] = *(const bf16x8*)(Al + ai);
      bh[i] = *(const bf16x8*)(Bh + bi);
      bl[i] = *(const bf16x8*)(Bl + bi);
    }
#pragma unroll
    for (int i = 0; i < 4; ++i)
#pragma unroll
      for (int j = 0; j < 4; ++j) {
        acc[i][j] = MFMA_BF16(ah[i], bh[j], acc[i][j]);
        acc[i][j] = MFMA_BF16(al[i], bh[j], acc[i][j]);
        acc[i][j] = MFMA_BF16(ah[i], bl[j], acc[i][j]);
      }
    __syncthreads();
  }
  const float* bias = (p == 0 ? bq : (p == 1 ? bk : bv)) + depth * 512;
  if (p < 2) {
    bf16_t* Oh = (p == 0 ? Qh : Kh) + (size_t)b * 262144;
    uint8_t* Ol = (p == 0 ? Ql : Kl) + (size_t)b * 262144;
#pragma unroll
    for (int i = 0; i < 4; ++i)
#pragma unroll
      for (int j = 0; j < 4; ++j)
#pragma unroll
        for (int r = 0; r < 4; ++r) {
          const int rr = row0 + wm*64 + i*16 + (lane >> 4)*4 + r;
          const int cc = col0 + wn*64 + j*16 + (lane & 15);
          const float y = acc[i][j][r] + bias[rr];
          const bf16_t h = (bf16_t)y;
          Oh[(size_t)rr * 512 + cc] = h;
          Ol[(size_t)rr * 512 + cc] = fp8s_enc(y - (float)h);
        }
  } else {
    bf16_t* Ovh = Yvh + (size_t)b * 262144;
    bf16_t* Ovl = Yvl + (size_t)b * 262144;
#pragma unroll
    for (int i = 0; i < 4; ++i)
#pragma unroll
      for (int j = 0; j < 4; ++j)
#pragma unroll
        for (int r = 0; r < 4; ++r) {
          const int rr = row0 + wm*64 + i*16 + (lane >> 4)*4 + r;
          const int cc = col0 + wn*64 + j*16 + (lane & 15);
          const float y = acc[i][j][r] + bias[rr];
          const bf16_t h = (bf16_t)y;
          Ovh[(size_t)rr * 512 + cc] = h;
          Ovl[(size_t)rr * 512 + cc] = (bf16_t)(y - (float)h);
        }
  }
}

// ---------------------------------------------------------------------------
// BN stats from hi planes; one block per (p,o); 32768 samples -> scale/shift
// (hi-only stats: per-channel coherent shift cancels in softmax-over-batch)
// ---------------------------------------------------------------------------
__global__ __launch_bounds__(256) void bn_stats_kern(
    const bf16_t* __restrict__ Qh, const bf16_t* __restrict__ Kh,
    const bf16_t* __restrict__ Yvh,
    const float* __restrict__ gq, const float* __restrict__ gk, const float* __restrict__ gv,
    const float* __restrict__ betaq, const float* __restrict__ betak, const float* __restrict__ betav,
    int depth, float* __restrict__ scale, float* __restrict__ shift) {
  const int po = blockIdx.x;
  const int p = po >> 9, o = po & 511;
  const bf16_t* base = (p == 0 ? Qh : (p == 1 ? Kh : Yvh)) + (size_t)o * 512;
  float s = 0.f, ss = 0.f;
  const int tid = threadIdx.x;
  for (int i = tid; i < 8192; i += 256) {
    const int b = i >> 7;
    const int l4 = (i & 127) * 4;
    bf16x4 v = *(const bf16x4*)(base + (size_t)b * 262144 + l4);
#pragma unroll
    for (int j = 0; j < 4; ++j) { float f = (float)v[j]; s += f; ss += f * f; }
  }
#pragma unroll
  for (int off = 32; off > 0; off >>= 1) {
    s  += __shfl_down(s, off);
    ss += __shfl_down(ss, off);
  }
  __shared__ float rs[4], rss[4];
  const int lane = tid & 63, wid = tid >> 6;
  if (lane == 0) { rs[wid] = s; rss[wid] = ss; }
  __syncthreads();
  if (tid == 0) {
    const float S  = rs[0] + rs[1] + rs[2] + rs[3];
    const float SS = rss[0] + rss[1] + rss[2] + rss[3];
    const float mean = S * (1.f / 32768.f);
    float var = SS * (1.f / 32768.f) - mean * mean;
    var = fmaxf(var, 0.f);
    const float* gp = (p == 0 ? gq : (p == 1 ? gk : gv));
    const float* bp = (p == 0 ? betaq : (p == 1 ? betak : betav));
    const float gamma = gp[depth * 512 + o];
    const float beta  = bp[depth * 512 + o];
    const float sc = gamma * rsqrtf(var + 1e-5f);
    scale[po] = sc;
    shift[po] = beta - mean * sc;
  }
}

// norm+relu Q,K in place (hi bf16 + scaled-fp8 lo pairs)
__global__ __launch_bounds__(256) void norm_qk_kern(
    bf16_t* __restrict__ Qh, uint8_t* __restrict__ Ql,
    bf16_t* __restrict__ Kh, uint8_t* __restrict__ Kl,
    const float* __restrict__ scale, const float* __restrict__ shift) {
  const size_t i = ((size_t)blockIdx.x * 256 + threadIdx.x) * 4;
  const int p = (int)(i >> 24);
  const size_t j = i & 0xFFFFFF;
  const int o = (int)(j >> 9) & 511;
  const int po = p * 512 + o;
  const float sc = scale[po], sh = shift[po];
  bf16_t* H = (p == 0 ? Qh : Kh) + j;
  uint8_t* L = (p == 0 ? Ql : Kl) + j;
  bf16x4 hv = *(bf16x4*)H;
  uint32_t lv = *(uint32_t*)L;
  bf16x4 ho;
  uint32_t lo_out = 0;
#pragma unroll
  for (int k = 0; k < 4; ++k) {
    const float y = (float)hv[k] + fp8s_dec((uint8_t)(lv >> (8*k)));
    const float q = fmaxf(y * sc + sh, 0.f);
    const bf16_t h = (bf16_t)q;
    ho[k] = h;
    lo_out |= (uint32_t)fp8s_enc(q - (float)h) << (8*k);
  }
  *(bf16x4*)H = ho;
  *(uint32_t*)L = lo_out;
}

// norm+relu V and transpose: Yv(hi+bf16lo)[b][d][l] -> VT(hi+fp8s lo)[b][l][d]
__global__ __launch_bounds__(256) void norm_v_t_kern(
    const bf16_t* __restrict__ Yvh, const bf16_t* __restrict__ Yvl,
    const float* __restrict__ scale, const float* __restrict__ shift,
    bf16_t* __restrict__ VTh, uint8_t* __restrict__ VTl) {
  __shared__ float t[32][33];
  const int bz = blockIdx.x >> 8;
  const int ti = blockIdx.x & 255;
  const int td = (ti >> 4) * 32;
  const int tl = (ti & 15) * 32;
  const size_t boff = (size_t)bz * 262144;
  const int tx = threadIdx.x & 31, ty = threadIdx.x >> 5;
#pragma unroll
  for (int k = 0; k < 4; ++k) {
    const int dd = td + ty*4 + k;
    const float sc = scale[1024 + dd], sh = shift[1024 + dd];
    const size_t o = boff + (size_t)dd * 512 + tl + tx;
    const float f = (float)Yvh[o] + (float)Yvl[o];
    t[ty*4+k][tx] = fmaxf(f * sc + sh, 0.f);
  }
  __syncthreads();
#pragma unroll
  for (int k = 0; k < 4; ++k) {
    const float v = t[tx][ty*4+k];
    const bf16_t h = (bf16_t)v;
    const size_t o = boff + (size_t)(tl + ty*4 + k)*512 + td + tx;
    VTh[o] = h;
    VTl[o] = fp8s_enc(v - (float)h);
  }
}

// ---------------------------------------------------------------------------
// w[b][c][d] = Q[c][l].K[d][l], f32 out, 3-term hi/lo MFMA.
// ---------------------------------------------------------------------------
__global__ __launch_bounds__(256) void gemm_w_kern(
    const bf16_t* __restrict__ Qh, const uint8_t* __restrict__ Ql,
    const bf16_t* __restrict__ Kh, const uint8_t* __restrict__ Kl,
    float* __restrict__ w) {
  __shared__ __align__(16) bf16_t Ah[4096], Al[4096], Bh[4096], Bl[4096];
  const int blk = blockIdx.x;
  const int t = blk & 15;
  const int b = blk >> 4;
  const int row0 = (t >> 2) * 128, col0 = (t & 3) * 128;
  const bf16_t* A_hi = Qh + (size_t)b * 262144;
  const uint8_t* A_lo = Ql + (size_t)b * 262144;
  const bf16_t* B_hi = Kh + (size_t)b * 262144;
  const uint8_t* B_lo = Kl + (size_t)b * 262144;
  const int tid = threadIdx.x, lane = tid & 63, wid = tid >> 6;
  const int wm = wid >> 1, wn = wid & 1;
  const int sr = tid >> 2, scs = (tid & 3) * 8;
  const int frow = lane & 15, fk = (lane >> 4) * 8;
  const int lrow = tid >> 1, lhalf = (tid & 1) * 16;
  f32x4 acc[4][4] = {};
  bf16_t* lah = Ah + wid * 512;
  bf16_t* lbh = Bh + wid * 512;
  const bf16_t* gah = A_hi + (size_t)(row0 + sr) * 512 + scs;
  const bf16_t* gbh = B_hi + (size_t)(col0 + sr) * 512 + scs;
  const uint8_t* gal = A_lo + (size_t)(row0 + lrow) * 512 + lhalf;
  const uint8_t* gbl = B_lo + (size_t)(col0 + lrow) * 512 + lhalf;
  for (int ks = 0; ks < 16; ++ks) {
    const int k0 = ks * 32;
    load_lds16(gah + k0, lah); load_lds16(gah + 32768 + k0, lah + 2048);
    load_lds16(gbh + k0, lbh); load_lds16(gbh + 32768 + k0, lbh + 2048);
    {
      uint4 ra = *(const uint4*)(gal + k0);
      uint4 rb = *(const uint4*)(gbl + k0);
      uint8_t ba[16]; *(uint4*)ba = ra;
      uint8_t bb[16]; *(uint4*)bb = rb;
      bf16x8 a0, a1, b0, b1;
#pragma unroll
      for (int j = 0; j < 8; ++j) { a0[j] = (bf16_t)fp8s_dec(ba[j]); a1[j] = (bf16_t)fp8s_dec(ba[8+j]); }
#pragma unroll
      for (int j = 0; j < 8; ++j) { b0[j] = (bf16_t)fp8s_dec(bb[j]); b1[j] = (bf16_t)fp8s_dec(bb[8+j]); }
      *(bf16x8*)(Al + lrow*32 + lhalf)     = a0;
      *(bf16x8*)(Al + lrow*32 + lhalf + 8) = a1;
      *(bf16x8*)(Bl + lrow*32 + lhalf)     = b0;
      *(bf16x8*)(Bl + lrow*32 + lhalf + 8) = b1;
    }
    __syncthreads();
    bf16x8 ah[4], al[4], bh[4], bl[4];
#pragma unroll
    for (int i = 0; i < 4; ++i) {
      const int ai = (wm*64 + i*16 + frow)*32 + fk;
      const int bi = (wn*64 + i*16 + frow)*32 + fk;
      ah[i] = *(const bf16x8*)(Ah + ai);
      al[i] = *(const bf16x8*)(Al + ai);
      bh[i] = *(const bf16x8*)(Bh + bi);
      bl[i] = *(const bf16x8*)(Bl + bi);
    }
#pragma unroll
    for (int i = 0; i < 4; ++i)
#pragma unroll
      for (int j = 0; j < 4; ++j) {
        acc[i][j] = MFMA_BF16(ah[i], bh[j], acc[i][j]);
        acc[i][j] = MFMA_BF16(al[i], bh[j], acc[i][j]);
        acc[i][j] = MFMA_BF16(ah[i], bl[j], acc[i][j]);
      }
    __syncthreads();
  }
  float* wb = w + (size_t)b * 262144;
#pragma unroll
  for (int i = 0; i < 4; ++i)
#pragma unroll
    for (int j = 0; j < 4; ++j)
#pragma unroll
      for (int r = 0; r < 4; ++r) {
        const int rr = row0 + wm*64 + i*16 + (lane >> 4)*4 + r;
        const int cc = col0 + wn*64 + j*16 + (lane & 15);
        wb[(size_t)rr * 512 + cc] = acc[i][j][r];
      }
}

// softmax over batch axis, f32 IN PLACE (w -> a); thread owns one (c,d)
__global__ __launch_bounds__(256) void softmax_kern(float* __restrict__ w) {
  const int idx = blockIdx.x * 256 + threadIdx.x;
  float v[64];
#pragma unroll
  for (int b = 0; b < 64; ++b) v[b] = w[idx + (size_t)b * 262144];
  float m = v[0];
#pragma unroll
  for (int b = 1; b < 64; ++b) m = fmaxf(m, v[b]);
  float s = 0.f;
#pragma unroll
  for (int b = 0; b < 64; ++b) { v[b] = __expf(v[b] - m); s += v[b]; }
  const float inv = 1.f / s;
#pragma unroll
  for (int b = 0; b < 64; ++b) w[idx + (size_t)b * 262144] = v[b] * inv;
}

// x[b][l][c] = VT[b][l][d] . a[b][c][d]; A = VT hi+fp8s-lo, B = a f32 (split
// at stage time into bf16 hi+lo). 3-term MFMA. Out: x hi + fp8s lo.
__global__ __launch_bounds__(256) void gemm_x_kern(
    const bf16_t* __restrict__ VTh, const uint8_t* __restrict__ VTl,
    const float* __restrict__ a,
    bf16_t* __restrict__ xh, uint8_t* __restrict__ xl) {
  __shared__ __align__(16) bf16_t Ah[4096], Al[4096], Bh[4096], Bl[4096];
  const int blk = blockIdx.x;
  const int t = blk & 15;
  const int b = blk >> 4;
  const int row0 = (t >> 2) * 128, col0 = (t & 3) * 128;
  const bf16_t* Ahg = VTh + (size_t)b * 262144;
  const uint8_t* Alg = VTl + (size_t)b * 262144;
  const float*   Bg  = a   + (size_t)b * 262144;
  const int tid = threadIdx.x, lane = tid & 63, wid = tid >> 6;
  const int wm = wid >> 1, wn = wid & 1;
  const int sr = tid >> 2, scs = (tid & 3) * 8;
  const int frow = lane & 15, fk = (lane >> 4) * 8;
  const int lrow = tid >> 1, lhalf = (tid & 1) * 16;
  f32x4 acc[4][4] = {};
  bf16_t* lah = Ah + wid * 512;
  const bf16_t* gah = Ahg + (size_t)(row0 + sr) * 512 + scs;
  const uint8_t* gal = Alg + (size_t)(row0 + lrow) * 512 + lhalf;
  for (int ks = 0; ks < 16; ++ks) {
    const int k0 = ks * 32;
    load_lds16(gah + k0, lah); load_lds16(gah + 32768 + k0, lah + 2048);
    { // A-lo: scaled-fp8 -> bf16 LDS
      uint4 raw = *(const uint4*)(gal + k0);
      uint8_t by[16]; *(uint4*)by = raw;
      bf16x8 v0, v1;
#pragma unroll
      for (int j = 0; j < 8; ++j) v0[j] = (bf16_t)fp8s_dec(by[j]);
#pragma unroll
      for (int j = 0; j < 8; ++j) v1[j] = (bf16_t)fp8s_dec(by[8+j]);
      *(bf16x8*)(Al + lrow*32 + lhalf)     = v0;
      *(bf16x8*)(Al + lrow*32 + lhalf + 8) = v1;
    }
    { // B: f32 -> bf16 hi/lo split (exact)
#pragma unroll
      for (int p = 0; p < 4; ++p) {
        const int idx = p * 256 + tid;
        const int br = idx >> 3;
        const int cs = (idx & 7) * 4;
        float4 v4 = *(const float4*)(Bg + (size_t)(col0 + br) * 512 + k0 + cs);
        float f[4] = {v4.x, v4.y, v4.z, v4.w};
        bf16x4 hv, lv;
#pragma unroll
        for (int j = 0; j < 4; ++j) {
          bf16_t h = (bf16_t)f[j];
          hv[j] = h;
          lv[j] = (bf16_t)(f[j] - (float)h);
        }
        *(bf16x4*)(Bh + br*32 + cs) = hv;
        *(bf16x4*)(Bl + br*32 + cs) = lv;
      }
    }
    __syncthreads();
    bf16x8 ah[4], al[4], bh[4], bl[4];
#pragma unroll
    for (int i = 0; i < 4; ++i) {
      const int ai = (wm*64 + i*16 + frow)*32 + fk;
      const int bi = (wn*64 + i*16 + frow)*32 + fk;
      ah[i] = *(const bf16x8*)(Ah + ai);
      al[i] = *(const bf16x8*)(Al + ai);
      bh[i] = *(const bf16x8*)(Bh + bi);
      bl[i] = *(const bf16x8*)(Bl + bi);
    }
#pragma unroll
    for (int i = 0; i < 4; ++i)
#pragma unroll
      for (int j = 0; j < 4; ++j) {
        acc[i][j] = MFMA_BF16(ah[i], bh[j], acc[i][j]);
        acc[i][j] = MFMA_BF16(al[i], bh[j], acc[i][j]);
        acc[i][j] = MFMA_BF16(ah[i], bl[j], acc[i][j]);
      }
    __syncthreads();
  }
  bf16_t* xb = xh + (size_t)b * 262144;
  uint8_t* lb8 = xl + (size_t)b * 262144;
#pragma unroll
  for (int i = 0; i < 4; ++i)
#pragma unroll
    for (int j = 0; j < 4; ++j)
#pragma unroll
      for (int r = 0; r < 4; ++r) {
        const int rr = row0 + wm*64 + i*16 + (lane >> 4)*4 + r;
        const int cc = col0 + wn*64 + j*16 + (lane & 15);
        const float y = acc[i][j][r];
        const bf16_t h = (bf16_t)y;
        xb[(size_t)rr * 512 + cc] = h;
        lb8[(size_t)rr * 512 + cc] = fp8s_enc(y - (float)h);
      }
}

// final: x(hi+fp8s lo)[b][l][c] -> out[b][c][l] f32
__global__ __launch_bounds__(256) void out_transpose_kern(
    const bf16_t* __restrict__ xh, const uint8_t* __restrict__ xl,
    float* __restrict__ out) {
  __shared__ float t[32][33];
  const int bz = blockIdx.x >> 8;
  const int ti = blockIdx.x & 255;
  const int tl = (ti >> 4) * 32;
  const int tc = (ti & 15) * 32;
  const bf16_t* xb = xh + (size_t)bz * 262144;
  const uint8_t* lb = xl + (size_t)bz * 262144;
  float* ob = out + (size_t)bz * 262144;
  const int tx = threadIdx.x & 31, ty = threadIdx.x >> 5;
#pragma unroll
  for (int k = 0; k < 4; ++k) {
    const size_t o = (size_t)(tl + ty*4 + k)*512 + tc + tx;
    t[ty*4+k][tx] = (float)xb[o] + fp8s_dec(lb[o]);
  }
  __syncthreads();
#pragma unroll
  for (int k = 0; k < 4; ++k)
    ob[(size_t)(tc + ty*4 + k)*512 + tl + tx] = t[tx][ty*4+k];
}

// ---------------------------------------------------------------------------
extern "C" void kernel_launch(void* const* d_in, const int* in_sizes, int n_in,
                              void* d_out, int out_size, void* d_ws, size_t ws_size,
                              hipStream_t stream) {
  const float* P     = (const float*)d_in[0];
  const float* Wq    = (const float*)d_in[1];
  const float* bq    = (const float*)d_in[2];
  const float* gq    = (const float*)d_in[3];
  const float* betaq = (const float*)d_in[4];
  const float* Wk    = (const float*)d_in[5];
  const float* bk    = (const float*)d_in[6];
  const float* gk    = (const float*)d_in[7];
  const float* betak = (const float*)d_in[8];
  const float* Wv    = (const float*)d_in[9];
  const float* bv    = (const float*)d_in[10];
  const float* gv    = (const float*)d_in[11];
  const float* betav = (const float*)d_in[12];

  char* ws = (char*)d_ws;
  size_t off = 0;
  auto alloc = [&](size_t bytes) -> char* {
    char* p = ws + off;
    off += (bytes + 255) & ~(size_t)255;
    return p;
  };
  // Three rotating 3-byte slots (hi 32MB + lo8 16MB each): hold x / Q / K / VT
  bf16_t*  Sh[3]; uint8_t* Sl[3];
  for (int i = 0; i < 3; ++i) {
    Sh[i] = (bf16_t*) alloc(33554432);
    Sl[i] = (uint8_t*)alloc(16777216);
  }
  // E slot (64MB): Yv pre-norm (bf16 hi + bf16 lo) -> then w f32 -> a f32
  char* E = alloc(67108864);
  float*  w   = (float*)E;
  bf16_t* Yvh = (bf16_t*)E;
  bf16_t* Yvl = (bf16_t*)(E + 33554432);
  bf16_t* Whi = (bf16_t*)alloc(4718592);
  bf16_t* Wlo = (bf16_t*)alloc(4718592);
  float* scale = (float*)alloc(6144);
  float* shift = (float*)alloc(6144);
  // total ~227.6 MB (== R3's proven-safe footprint)
  // slot rotation: VT reuses the dead x slot; new-x reuses the dead Q (or K)
  // slot. d0: x@0 Q@1 K@2 VT@0 nx@1 | d1: x@1 Q@0 K@2 VT@1 nx@0 |
  // d2: x@0 Q@1 K@2 VT@0 nx@2; out reads slot 2.

  cast_w_kern<<<2304, 256, 0, stream>>>(Wq, Wk, Wv, Whi, Wlo);
  transpose_split_in_kern<<<16384, 256, 0, stream>>>(P, Sh[0], Sl[0]);
  for (int d = 0; d < 3; ++d) {
    const int xi = (d == 1) ? 1 : 0;
    const int qi = (d == 1) ? 0 : 1;
    const int ki = 2;
    const int ni = (d == 2) ? 2 : qi;
    gemm_qkv_kern<<<3072, 256, 0, stream>>>(Whi, Wlo, Sh[xi], Sl[xi],
        bq, bk, bv, d, Sh[qi], Sl[qi], Sh[ki], Sl[ki], Yvh, Yvl);
    bn_stats_kern<<<1536, 256, 0, stream>>>(Sh[qi], Sh[ki], Yvh,
        gq, gk, gv, betaq, betak, betav, d, scale, shift);
    norm_qk_kern<<<32768, 256, 0, stream>>>(Sh[qi], Sl[qi], Sh[ki], Sl[ki],
        scale, shift);
    norm_v_t_kern<<<16384, 256, 0, stream>>>(Yvh, Yvl, scale, shift,
        Sh[xi], Sl[xi]);
    gemm_w_kern<<<1024, 256, 0, stream>>>(Sh[qi], Sl[qi], Sh[ki], Sl[ki], w);
    softmax_kern<<<1024, 256, 0, stream>>>(w);
    gemm_x_kern<<<1024, 256, 0, stream>>>(Sh[xi], Sl[xi], w, Sh[ni], Sl[ni]);
  }
  out_transpose_kern<<<16384, 256, 0, stream>>>(Sh[2], Sl[2], (float*)d_out);
}